// Round 10
// baseline (824.847 us; speedup 1.0000x reference)
//
#include <hip/hip_runtime.h>
#include <hip/hip_bf16.h>

typedef __bf16 bfv8 __attribute__((ext_vector_type(8)));
typedef __bf16 bfv4 __attribute__((ext_vector_type(4)));
typedef float f32x4 __attribute__((ext_vector_type(4)));
typedef unsigned int u32x2 __attribute__((ext_vector_type(2)));
typedef unsigned short u16;
typedef unsigned int u32;

#define MT 78400   // total tokens = 400*196

#define SBAR() __builtin_amdgcn_s_barrier()
#define VMCNT(n) asm volatile("s_waitcnt vmcnt(" #n ")" ::: "memory")
#define LGKM0() asm volatile("s_waitcnt lgkmcnt(0)" ::: "memory")
#define SCHEDB() __builtin_amdgcn_sched_barrier(0)

__device__ __forceinline__ u16 f2bf(float f) {
  u32 x = __float_as_uint(f);
  return (u16)((x + 0x7FFFu + ((x >> 16) & 1u)) >> 16);
}

__device__ __forceinline__ void gld16(const void* g, void* l) {
  __builtin_amdgcn_global_load_lds((const __attribute__((address_space(1))) void*)g,
                                   (__attribute__((address_space(3))) void*)l, 16, 0, 0);
}

// 8 f32 -> 8 bf16 (RTNE, matches f2bf) -> ds_write_b128
__device__ __forceinline__ void cvtwr(u16* d, f32x4 a, f32x4 b) {
  u32 p0, p1, p2, p3;
  asm("v_cvt_pk_bf16_f32 %0, %1, %2" : "=v"(p0) : "v"(a[0]), "v"(a[1]));
  asm("v_cvt_pk_bf16_f32 %0, %1, %2" : "=v"(p1) : "v"(a[2]), "v"(a[3]));
  asm("v_cvt_pk_bf16_f32 %0, %1, %2" : "=v"(p2) : "v"(b[0]), "v"(b[1]));
  asm("v_cvt_pk_bf16_f32 %0, %1, %2" : "=v"(p3) : "v"(b[2]), "v"(b[3]));
  uint4 o = {p0, p1, p2, p3};
  *(uint4*)d = o;
}

// ---------------- fp32 -> bf16 convert (weights only now) ----------------
__global__ __launch_bounds__(256) void cvt_f32_bf16(const float* __restrict__ src,
                                                    u16* __restrict__ dst, int n8) {
  int stride = gridDim.x * 256;
  for (int i = blockIdx.x * 256 + threadIdx.x; i < n8; i += stride) {
    const float4* s = (const float4*)(src + (long)i * 8);
    float4 a = s[0], b = s[1];
    u32 p0 = f2bf(a.x) | ((u32)f2bf(a.y) << 16);
    u32 p1 = f2bf(a.z) | ((u32)f2bf(a.w) << 16);
    u32 p2 = f2bf(b.x) | ((u32)f2bf(b.y) << 16);
    u32 p3 = f2bf(b.z) | ((u32)f2bf(b.w) << 16);
    uint4 o = {p0, p1, p2, p3};
    *(uint4*)(dst + (long)i * 8) = o;
  }
}

// ---------------- one-hot indicator table for rel-pos bias (global const) ----------------
__global__ __launch_bounds__(256) void indk_init(u16* __restrict__ T) {
  int i = blockIdx.x * 256 + threadIdx.x;
  if (i < 208 * 40) {
    int k = i / 40, j = i - (i / 40) * 40;
    int hk = k / 14, wk = k - hk * 14;
    T[i] = (j == hk || j == 16 + wk) ? 0x3F80 : 0;
  }
}

// ================= 256x256 / BK=64 / 8-wave GEMM core =================
// Round 10: retry of the fused-convert with COMPILER-managed A loads (round 9's
// asm global_load was the crash suspect: async write-back the compiler can't
// model). Plain f32x4 loads: compiler inserts exact waits before av uses; my
// VMCNT(4) only needs to confirm B(u+1), which is the OLDEST 4 of <=16
// outstanding ops under any interleave -> unconditionally completed.
// sched_barrier(0) pins load issue to the intended phase (raw s_barrier is not
// a compiler fence). LGKM0 after WRA drains swizzled ds_writes pre-barrier.
// F32A=false (proj): byte-identical to the round-3/8 verified path.
template<bool F32A>
__device__ __forceinline__ void gemm256_core(const void* Ain, const u16* __restrict__ W,
                                             u16* SH, int m0, int n0, int tid,
                                             f32x4 (&acc)[8][4]) {
  const int lane = tid & 63;
  const int q15 = lane & 15, g = lane >> 4;
  const int wid = tid >> 6;
  const int wm = wid >> 2, wn = wid & 3;   // 2 x 4 waves; per-wave C = 128 x 64
  const int x0 = (g ^ (q15 & 7)) << 3;     // swizzled u16 offset of ksub0 (ksub1 = x0^32)
  const int arow0 = wm * 128 + q15;
  const int brow0 = wn * 64 + q15;

  const int r0 = tid >> 3;
  const int cc8 = tid & 7;
  const int gc0 = (cc8 ^ (r0 & 7)) << 3;   // swizzle offset (u16)
  int ra0 = m0 + r0;       if (ra0 > MT - 1) ra0 = MT - 1;
  int ra1 = m0 + 64 + r0;  if (ra1 > MT - 1) ra1 = MT - 1;
  int ra2 = m0 + 128 + r0; if (ra2 > MT - 1) ra2 = MT - 1;
  int ra3 = m0 + 192 + r0; if (ra3 > MT - 1) ra3 = MT - 1;

  // B staging sources (bf16, pre-swizzled) — unchanged
  const u16* bS00 = W + (long)(n0 + r0) * 768 + gc0;
  const u16* bS10 = W + (long)(n0 + 64 + r0) * 768 + gc0;
  const u16* bS01 = W + (long)(n0 + 128 + r0) * 768 + gc0;
  const u16* bS11 = W + (long)(n0 + 192 + r0) * 768 + gc0;
  u16* dB = SH + 16384 + tid * 8;

  auto STGB = [&](int sl, const u16* p0, const u16* p1, int hoff, int kt) {
    u16* d = dB + sl * 32768 + hoff;
    gld16(p0 + kt * 64, d);
    gld16(p1 + kt * 64, d + 4096);
  };

  // A path: bf16 gld_lds (proj) — pre-swizzled source, linear dest
  const u16* aS00 = nullptr; const u16* aS10 = nullptr;
  const u16* aS01 = nullptr; const u16* aS11 = nullptr;
  u16* dA = SH + tid * 8;
  // A path: f32 reg-staging (qkv) — linear source, swizzled dest
  const float* aF0 = nullptr; const float* aF1 = nullptr;
  const float* aF2 = nullptr; const float* aF3 = nullptr;
  u16* wd0 = SH + r0 * 64 + gc0;           // + slot*32768 (+4096 row+64, +8192 half1)
  if constexpr (F32A) {
    const float* Af = (const float*)Ain;
    aF0 = Af + (long)ra0 * 768 + cc8 * 8;
    aF1 = Af + (long)ra1 * 768 + cc8 * 8;
    aF2 = Af + (long)ra2 * 768 + cc8 * 8;
    aF3 = Af + (long)ra3 * 768 + cc8 * 8;
  } else {
    const u16* Ab = (const u16*)Ain;
    aS00 = Ab + (long)ra0 * 768 + gc0;
    aS10 = Ab + (long)ra1 * 768 + gc0;
    aS01 = Ab + (long)ra2 * 768 + gc0;
    aS11 = Ab + (long)ra3 * 768 + gc0;
  }
  auto STGA = [&](int sl, const u16* p0, const u16* p1, int hoff, int kt) {
    u16* d = dA + sl * 32768 + hoff;
    gld16(p0 + kt * 64, d);
    gld16(p1 + kt * 64, d + 4096);
  };

  f32x4 av0, av1, av2, av3, av4, av5, av6, av7;     // A(u+2) staging regs
  auto LDA0 = [&](int kt) {                // half0: 4 x dwordx4 (compiler loads)
    av0 = *(const f32x4*)(aF0 + kt * 64);
    av1 = *(const f32x4*)(aF0 + kt * 64 + 4);
    av2 = *(const f32x4*)(aF1 + kt * 64);
    av3 = *(const f32x4*)(aF1 + kt * 64 + 4);
  };
  auto LDA1 = [&](int kt) {                // half1
    av4 = *(const f32x4*)(aF2 + kt * 64);
    av5 = *(const f32x4*)(aF2 + kt * 64 + 4);
    av6 = *(const f32x4*)(aF3 + kt * 64);
    av7 = *(const f32x4*)(aF3 + kt * 64 + 4);
  };
  auto WRA = [&](int sl) {                 // cvt + 4 swizzled ds_write_b128
    u16* d = wd0 + sl * 32768;
    cvtwr(d, av0, av1);
    cvtwr(d + 4096, av2, av3);
    cvtwr(d + 8192, av4, av5);
    cvtwr(d + 12288, av6, av7);
  };

  bfv8 b0[4], b1[4];
  bfv8 aX0[2], aX1[2], aY0[2], aY1[2];

  // ---- prologue ----
  if constexpr (F32A) {
    LDA0(0); LDA1(0);
    SCHEDB();
    STGB(0, bS00, bS10, 0, 0); STGB(0, bS01, bS11, 8192, 0);
    STGB(1, bS00, bS10, 0, 1); STGB(1, bS01, bS11, 8192, 1);
    VMCNT(8);                                          // A(0) (oldest 8) landed
    WRA(0);
    LDA0(1); LDA1(1);
    VMCNT(0);                                          // everything landed
    WRA(1);
    LGKM0();                                           // drain ds_writes pre-barrier
  } else {
    STGB(0, bS00, bS10, 0, 0); STGB(0, bS01, bS11, 8192, 0);
    STGA(0, aS00, aS10, 0, 0); STGA(0, aS01, aS11, 8192, 0);
    STGB(1, bS00, bS10, 0, 1); STGB(1, bS01, bS11, 8192, 1);
    STGA(1, aS00, aS10, 0, 1);
    VMCNT(4);
  }
  SBAR();
  {
    const u16* Sb = SH + 16384;
#pragma unroll
    for (int ni = 0; ni < 4; ++ni) {
      const u16* bp = Sb + (brow0 + ni * 16) * 64;
      b0[ni] = *(const bfv8*)(bp + x0);
      b1[ni] = *(const bfv8*)(bp + (x0 ^ 32));
    }
#pragma unroll
    for (int m2 = 0; m2 < 2; ++m2) {
      const u16* ap = SH + (arow0 + m2 * 16) * 64;
      aX0[m2] = *(const bfv8*)(ap + x0);
      aX1[m2] = *(const bfv8*)(ap + (x0 ^ 32));
    }
  }

  for (int u = 0; u < 12; ++u) {
    const int sl = u & 1;
    const u16* Sa = SH + sl * 32768;
    const u16* San = SH + (sl ^ 1) * 32768;
    const u16* Sbn = San + 16384;
    const int kn1 = (u + 1 < 12) ? u + 1 : 11;
    const int kn2 = (u + 2 < 12) ? u + 2 : 11;

    // ---- q0: MFMA quad0 (X); SBAR; read quad1->Y; issue A(u+2) half0 ----
    __builtin_amdgcn_s_setprio(1);
#pragma unroll
    for (int m2 = 0; m2 < 2; ++m2)
#pragma unroll
      for (int ni = 0; ni < 4; ++ni)
        acc[m2][ni] = __builtin_amdgcn_mfma_f32_16x16x32_bf16(aX0[m2], b0[ni], acc[m2][ni], 0, 0, 0);
#pragma unroll
    for (int m2 = 0; m2 < 2; ++m2)
#pragma unroll
      for (int ni = 0; ni < 4; ++ni)
        acc[m2][ni] = __builtin_amdgcn_mfma_f32_16x16x32_bf16(aX1[m2], b1[ni], acc[m2][ni], 0, 0, 0);
    __builtin_amdgcn_s_setprio(0);
    SBAR();
#pragma unroll
    for (int m2 = 0; m2 < 2; ++m2) {
      const u16* ap = Sa + (arow0 + (2 + m2) * 16) * 64;
      aY0[m2] = *(const bfv8*)(ap + x0);
      aY1[m2] = *(const bfv8*)(ap + (x0 ^ 32));
    }
    if constexpr (F32A) { LDA0(kn2); SCHEDB(); }
    else STGA(sl ^ 1, aS01, aS11, 8192, kn1);

    // ---- q1: MFMA quad1 (Y); SBAR; read quad2->X; issue A half1; stage B(u+2)h0 ----
    __builtin_amdgcn_s_setprio(1);
#pragma unroll
    for (int m2 = 0; m2 < 2; ++m2)
#pragma unroll
      for (int ni = 0; ni < 4; ++ni)
        acc[2 + m2][ni] = __builtin_amdgcn_mfma_f32_16x16x32_bf16(aY0[m2], b0[ni], acc[2 + m2][ni], 0, 0, 0);
#pragma unroll
    for (int m2 = 0; m2 < 2; ++m2)
#pragma unroll
      for (int ni = 0; ni < 4; ++ni)
        acc[2 + m2][ni] = __builtin_amdgcn_mfma_f32_16x16x32_bf16(aY1[m2], b1[ni], acc[2 + m2][ni], 0, 0, 0);
    __builtin_amdgcn_s_setprio(0);
    SBAR();
#pragma unroll
    for (int m2 = 0; m2 < 2; ++m2) {
      const u16* ap = Sa + (arow0 + (4 + m2) * 16) * 64;
      aX0[m2] = *(const bfv8*)(ap + x0);
      aX1[m2] = *(const bfv8*)(ap + (x0 ^ 32));
    }
    if constexpr (F32A) { LDA1(kn2); SCHEDB(); }
    STGB(sl, bS00, bS10, 0, kn2);

    // ---- q2: MFMA quad2 (X); SBAR; read quad3->Y; stage B(u+2)h1 ----
    __builtin_amdgcn_s_setprio(1);
#pragma unroll
    for (int m2 = 0; m2 < 2; ++m2)
#pragma unroll
      for (int ni = 0; ni < 4; ++ni)
        acc[4 + m2][ni] = __builtin_amdgcn_mfma_f32_16x16x32_bf16(aX0[m2], b0[ni], acc[4 + m2][ni], 0, 0, 0);
#pragma unroll
    for (int m2 = 0; m2 < 2; ++m2)
#pragma unroll
      for (int ni = 0; ni < 4; ++ni)
        acc[4 + m2][ni] = __builtin_amdgcn_mfma_f32_16x16x32_bf16(aX1[m2], b1[ni], acc[4 + m2][ni], 0, 0, 0);
    __builtin_amdgcn_s_setprio(0);
    SBAR();
#pragma unroll
    for (int m2 = 0; m2 < 2; ++m2) {
      const u16* ap = Sa + (arow0 + (6 + m2) * 16) * 64;
      aY0[m2] = *(const bfv8*)(ap + x0);
      aY1[m2] = *(const bfv8*)(ap + (x0 ^ 32));
    }
    STGB(sl, bS01, bS11, 8192, kn2);

    // ---- q3: MFMA quad3 (Y); VMCNT(4); SBAR; [cvt+write A(u+2)]; read nextB+quad0 ----
    __builtin_amdgcn_s_setprio(1);
#pragma unroll
    for (int m2 = 0; m2 < 2; ++m2)
#pragma unroll
      for (int ni = 0; ni < 4; ++ni)
        acc[6 + m2][ni] = __builtin_amdgcn_mfma_f32_16x16x32_bf16(aY0[m2], b0[ni], acc[6 + m2][ni], 0, 0, 0);
#pragma unroll
    for (int m2 = 0; m2 < 2; ++m2)
#pragma unroll
      for (int ni = 0; ni < 4; ++ni)
        acc[6 + m2][ni] = __builtin_amdgcn_mfma_f32_16x16x32_bf16(aY1[m2], b1[ni], acc[6 + m2][ni], 0, 0, 0);
    __builtin_amdgcn_s_setprio(0);
    VMCNT(4);     // B(u+1) = oldest 4 of <=16 outstanding -> confirmed under any interleave
    SBAR();
    if constexpr (F32A) { WRA(sl); LGKM0(); }   // slot-sl A(u) reads consumed pre-barrier
    else STGA(sl, aS00, aS10, 0, kn2);
    if (u < 11) {
#pragma unroll
      for (int ni = 0; ni < 4; ++ni) {
        const u16* bp = Sbn + (brow0 + ni * 16) * 64;
        b0[ni] = *(const bfv8*)(bp + x0);
        b1[ni] = *(const bfv8*)(bp + (x0 ^ 32));
      }
#pragma unroll
      for (int m2 = 0; m2 < 2; ++m2) {
        const u16* ap = San + (arow0 + m2 * 16) * 64;
        aX0[m2] = *(const bfv8*)(ap + x0);
        aX1[m2] = *(const bfv8*)(ap + (x0 ^ 32));
      }
    }
  }
  VMCNT(0);
}

// ---------------- QKV GEMM: 256x256, A = f32 hs (fused convert) ----------------
// grid = 307 x 9 = 2763; bijective XCD chunking (q=345, r=3).
__global__ __launch_bounds__(512) void qkv_gemm(const float* __restrict__ A, const u16* __restrict__ W,
                                                const float* __restrict__ bias,
                                                u16* __restrict__ Qo, u16* __restrict__ Ko,
                                                u16* __restrict__ Vo) {
  extern __shared__ u16 SH[];
  const int tid = threadIdx.x;
  const int orig = blockIdx.x;
  const int xcd = orig & 7, ii = orig >> 3;
  const int wg = (xcd < 3 ? xcd * 346 : 1038 + (xcd - 3) * 345) + ii;
  const int mt = wg / 9, nt = wg - mt * 9;
  const int m0 = mt * 256, n0 = nt * 256;

  f32x4 acc[8][4];
#pragma unroll
  for (int i = 0; i < 8; ++i)
#pragma unroll
    for (int j = 0; j < 4; ++j) acc[i][j] = (f32x4){0.f, 0.f, 0.f, 0.f};

  gemm256_core<true>(A, W, SH, m0, n0, tid, acc);

  const int lane = tid & 63, q15 = lane & 15, g = lane >> 4;
  const int wid = tid >> 6, wm = wid >> 2, wn = wid & 3;
  __syncthreads();
  const int sel = nt / 3;
  u16* dst = (sel == 0) ? Qo : (sel == 1) ? Ko : Vo;
  const int ntr = nt - sel * 3;
  u16* Cs = SH;                             // [128][264]

#pragma unroll
  for (int h = 0; h < 2; ++h) {
    if (wm == h) {
#pragma unroll
      for (int ni = 0; ni < 4; ++ni) {
        int col = wn * 64 + ni * 16 + q15;
        float bb = bias[n0 + col];
#pragma unroll
        for (int mi = 0; mi < 8; ++mi)
#pragma unroll
          for (int r = 0; r < 4; ++r)
            Cs[(mi * 16 + g * 4 + r) * 264 + col] = f2bf(acc[mi][ni][r] + bb);
      }
    }
    __syncthreads();
#pragma unroll
    for (int j = 0; j < 8; ++j) {
      int idx = tid + 512 * j;
      int row = idx >> 5, cc = idx & 31;
      int m = m0 + h * 128 + row;
      if (m < MT) {
        int b = m / 196, s = m - b * 196;
        int nh = ntr * 4 + (cc >> 3);
        int hd0 = (cc & 7) * 8;
        uint4 v = *(const uint4*)(Cs + row * 264 + cc * 8);
        *(uint4*)(dst + (long)b * 150528 + (long)s * 64 + nh * 12544 + hd0) = v;
      }
    }
    if (h == 0) __syncthreads();
  }
}

// ---------------- Proj GEMM: 256x256, bf16 A, f32 output ----------------
__global__ __launch_bounds__(512, 2) void proj_gemm(const u16* __restrict__ A, const u16* __restrict__ W,
                                                    const float* __restrict__ bias,
                                                    float* __restrict__ out) {
  extern __shared__ u16 SH[];
  const int tid = threadIdx.x;
  const int orig = blockIdx.x;
  const int xcd = orig & 7, ii = orig >> 3;
  const int wg = (xcd < 1 ? xcd * 116 : 116 + (xcd - 1) * 115) + ii;
  const int mt = wg / 3, nt = wg - mt * 3;
  const int m0 = mt * 256, n0 = nt * 256;

  f32x4 acc[8][4];
#pragma unroll
  for (int i = 0; i < 8; ++i)
#pragma unroll
    for (int j = 0; j < 4; ++j) acc[i][j] = (f32x4){0.f, 0.f, 0.f, 0.f};

  gemm256_core<false>(A, W, SH, m0, n0, tid, acc);

  const int lane = tid & 63, q15 = lane & 15, g = lane >> 4;
  const int wid = tid >> 6, wm = wid >> 2, wn = wid & 3;

#pragma unroll
  for (int ni = 0; ni < 4; ++ni) {
    int n = n0 + wn * 64 + ni * 16 + q15;
    float bb = bias[n];
#pragma unroll
    for (int mi = 0; mi < 8; ++mi)
#pragma unroll
      for (int r = 0; r < 4; ++r) {
        int m = m0 + wm * 128 + mi * 16 + g * 4 + r;
        if (m < MT) out[(long)m * 768 + n] = acc[mi][ni][r] + bb;
      }
  }
}

// ---------------- fused rel-pos attention (round-8 double-tile, unchanged) ----------------
#define KLDS_OFF 0          // 208*64*2   = 26624
#define VT_OFF   26624      // 64*256*2   = 32768
#define TH_OFF   59392      // 27*72*2    = 3888
#define TW_OFF   63280      // 3888
#define AW_OFF   67168      // 8*16*40*2  = 10240
#define SMEM_SZ  77408

__global__ __launch_bounds__(512, 2) void attn_kernel(const u16* __restrict__ Q, const u16* __restrict__ K,
                                                      const u16* __restrict__ V,
                                                      const float* __restrict__ rph, const float* __restrict__ rpw,
                                                      const u16* __restrict__ IndKg,
                                                      u16* __restrict__ AO) {
  extern __shared__ char smem[];
  u16* Klds = (u16*)(smem + KLDS_OFF);
  u16* VT = (u16*)(smem + VT_OFF);
  u16* TH = (u16*)(smem + TH_OFF);
  u16* TW = (u16*)(smem + TW_OFF);
  const int tid = threadIdx.x, lane = tid & 63, wid = tid >> 6;
  const int q15 = lane & 15, g = lane >> 4;
  const int bnh = blockIdx.x;
  const int b = bnh / 12, nh = bnh - b * 12;
  const u16* Qg = Q + bnh * 12544;
  const u16* Kg = K + bnh * 12544;
  const u16* Vg = V + bnh * 12544;
  u16* AWw = (u16*)(smem + AW_OFF) + wid * 16 * 40;

  for (int c = tid; c < 1568; c += 512) {
    int krow = c >> 3, part = c & 7;
    gld16(Kg + krow * 64 + ((part ^ (krow & 7)) << 3), Klds + c * 8);
  }
  for (int idx = tid; idx < 1792; idx += 512) {
    int k = idx >> 3, nb = idx & 7;
    u32 w0 = 0, w1 = 0, w2 = 0, w3 = 0;
    if (k < 196) {
      uint4 t = *(const uint4*)(Vg + k * 64 + nb * 8);
      w0 = t.x; w1 = t.y; w2 = t.z; w3 = t.w;
    }
    u32 wv[4] = {w0, w1, w2, w3};
#pragma unroll
    for (int j = 0; j < 8; j++) {
      int n = nb * 8 + j;
      u16 val = (u16)(wv[j >> 1] >> ((j & 1) * 16));
      int blk = (k >> 3) ^ (n & 7) ^ (n >> 3);
      VT[n * 256 + blk * 8 + (k & 7)] = val;
    }
  }
  for (int i = tid; i < 27 * 64; i += 512) {
    int r = i >> 6, cc = i & 63;
    TH[r * 72 + cc] = f2bf(rph[i]);
    TW[r * 72 + cc] = f2bf(rpw[i]);
  }
  __syncthreads();

  const int ksw = q15 & 7;
  const int ko0 = (g ^ ksw) << 3;
  const int ko1 = ((g + 4) ^ ksw) << 3;
  const f32x4 zero = {0.f, 0.f, 0.f, 0.f};

  auto mk_qaug = [&](int tq0, bfv8 qf0, bfv8 qf1) -> bfv8 {
    int hq0 = tq0 / 14, hq1 = (tq0 + 15) / 14;
    int rha = hq0 + 13 - q15; rha = rha < 0 ? 0 : (rha > 26 ? 26 : rha);
    int rhb = hq1 + 13 - q15; rhb = rhb < 0 ? 0 : (rhb > 26 ? 26 : rhb);
    int rwa = q15;
    int rwb = 16 + q15; if (rwb > 26) rwb = 26;
    f32x4 c0h = zero, c1h = zero, c0w = zero, c1w = zero;
    {
      bfv8 t0 = *(const bfv8*)(TH + rha * 72 + g * 8);
      bfv8 t1 = *(const bfv8*)(TH + rha * 72 + 32 + g * 8);
      c0h = __builtin_amdgcn_mfma_f32_16x16x32_bf16(qf0, t0, c0h, 0, 0, 0);
      c0h = __builtin_amdgcn_mfma_f32_16x16x32_bf16(qf1, t1, c0h, 0, 0, 0);
      bfv8 t2 = *(const bfv8*)(TH + rhb * 72 + g * 8);
      bfv8 t3 = *(const bfv8*)(TH + rhb * 72 + 32 + g * 8);
      c1h = __builtin_amdgcn_mfma_f32_16x16x32_bf16(qf0, t2, c1h, 0, 0, 0);
      c1h = __builtin_amdgcn_mfma_f32_16x16x32_bf16(qf1, t3, c1h, 0, 0, 0);
      bfv8 u0 = *(const bfv8*)(TW + rwa * 72 + g * 8);
      bfv8 u1 = *(const bfv8*)(TW + rwa * 72 + 32 + g * 8);
      c0w = __builtin_amdgcn_mfma_f32_16x16x32_bf16(qf0, u0, c0w, 0, 0, 0);
      c0w = __builtin_amdgcn_mfma_f32_16x16x32_bf16(qf1, u1, c0w, 0, 0, 0);
      bfv8 u2 = *(const bfv8*)(TW + rwb * 72 + g * 8);
      bfv8 u3 = *(const bfv8*)(TW + rwb * 72 + 32 + g * 8);
      c1w = __builtin_amdgcn_mfma_f32_16x16x32_bf16(qf0, u2, c1w, 0, 0, 0);
      c1w = __builtin_amdgcn_mfma_f32_16x16x32_bf16(qf1, u3, c1w, 0, 0, 0);
    }
#pragma unroll
    for (int r = 0; r < 4; r++) {
      int row = g * 4 + r;
      int qq = tq0 + row;
      int hqr = qq / 14;
      int wq_r = qq - hqr * 14;
      if (q15 < 10) AWw[row * 40 + 30 + q15] = 0;
      float rh = ((hqr == hq1) ? c1h[r] : c0h[r]) * 8.0f;
      AWw[row * 40 + q15] = (q15 <= 13) ? f2bf(rh) : (u16)0;
      int w0p = wq_r + 13 - q15;
      if (w0p >= 0 && w0p <= 13) AWw[row * 40 + 16 + w0p] = f2bf(c0w[r] * 8.0f);
      int w1p = wq_r - 3 - q15;
      if (w1p >= 0 && w1p <= 13) AWw[row * 40 + 16 + w1p] = f2bf(c1w[r] * 8.0f);
    }
    return *(const bfv8*)(AWw + q15 * 40 + g * 8);
  };

  if (wid < 7) {
    const int q0 = wid * 32;
    int qrA = q0 + q15;      if (qrA > 195) qrA = 195;
    int qrB = q0 + 16 + q15; if (qrB > 195) qrB = 195;
    bfv8 qf0A = *(const bfv8*)(Qg + qrA * 64 + g * 8);
    bfv8 qf1A = *(const bfv8*)(Qg + qrA * 64 + 32 + g * 8);
    bfv8 qf0B = *(const bfv8*)(Qg + qrB * 64 + g * 8);
    bfv8 qf1B = *(const bfv8*)(Qg + qrB * 64 + 32 + g * 8);

    bfv8 qaugA = mk_qaug(q0, qf0A, qf1A);
    bfv8 qaugB = mk_qaug(q0 + 16, qf0B, qf1B);

    f32x4 oA[4] = {zero, zero, zero, zero};
    f32x4 oB[4] = {zero, zero, zero, zero};
    float denA = 0.f, denB = 0.f;
#pragma unroll
    for (int t = 0; t < 13; t++) {
      const u16* kr = Klds + (t * 16 + q15) * 64;
      bfv8 kb0 = *(const bfv8*)(kr + ko0);
      bfv8 kb1 = *(const bfv8*)(kr + ko1);
      bfv8 ib = *(const bfv8*)(IndKg + (t * 16 + q15) * 40 + g * 8);
      __builtin_amdgcn_s_setprio(1);
      f32x4 aA = __builtin_amdgcn_mfma_f32_16x16x32_bf16(ib, qaugA, zero, 0, 0, 0);
      f32x4 aB = __builtin_amdgcn_mfma_f32_16x16x32_bf16(ib, qaugB, zero, 0, 0, 0);
      aA = __builtin_amdgcn_mfma_f32_16x16x32_bf16(kb0, qf0A, aA, 0, 0, 0);
      aB = __builtin_amdgcn_mfma_f32_16x16x32_bf16(kb0, qf0B, aB, 0, 0, 0);
      f32x4 sA = __builtin_amdgcn_mfma_f32_16x16x32_bf16(kb1, qf1A, aA, 0, 0, 0);
      f32x4 sB = __builtin_amdgcn_mfma_f32_16x16x32_bf16(kb1, qf1B, aB, 0, 0, 0);
      __builtin_amdgcn_s_setprio(0);
      const bool msk = (t == 12 && g > 0);
      float pA0 = msk ? 0.f : exp2f(sA[0] * 0.18033688f - 5.7707802f);
      float pA1 = msk ? 0.f : exp2f(sA[1] * 0.18033688f - 5.7707802f);
      float pA2 = msk ? 0.f : exp2f(sA[2] * 0.18033688f - 5.7707802f);
      float pA3 = msk ? 0.f : exp2f(sA[3] * 0.18033688f - 5.7707802f);
      float pB0 = msk ? 0.f : exp2f(sB[0] * 0.18033688f - 5.7707802f);
      float pB1 = msk ? 0.f : exp2f(sB[1] * 0.18033688f - 5.7707802f);
      float pB2 = msk ? 0.f : exp2f(sB[2] * 0.18033688f - 5.7707802f);
      float pB3 = msk ? 0.f : exp2f(sB[3] * 0.18033688f - 5.7707802f);
      denA += (pA0 + pA1) + (pA2 + pA3);
      denB += (pB0 + pB1) + (pB2 + pB3);
      u32 loA, hiA, loB, hiB;
      asm("v_cvt_pk_bf16_f32 %0, %1, %2" : "=v"(loA) : "v"(pA0), "v"(pA1));
      asm("v_cvt_pk_bf16_f32 %0, %1, %2" : "=v"(hiA) : "v"(pA2), "v"(pA3));
      asm("v_cvt_pk_bf16_f32 %0, %1, %2" : "=v"(loB) : "v"(pB0), "v"(pB1));
      asm("v_cvt_pk_bf16_f32 %0, %1, %2" : "=v"(hiB) : "v"(pB2), "v"(pB3));
      u32x2 wA; wA.x = loA; wA.y = hiA;
      u32x2 wB; wB.x = loB; wB.y = hiB;
      bfv4 paA = __builtin_bit_cast(bfv4, wA);
      bfv4 paB = __builtin_bit_cast(bfv4, wB);
      const int kblk = 2 * t + (g >> 1);
      const int koff = (g & 1) * 4;
      __builtin_amdgcn_s_setprio(1);
#pragma unroll
      for (int nt_ = 0; nt_ < 4; nt_++) {
        int n = nt_ * 16 + q15;
        int blk = (kblk ^ (n & 7) ^ (n >> 3));
        bfv4 vb = *(const bfv4*)(VT + n * 256 + blk * 8 + koff);
        asm("v_mfma_f32_16x16x16_bf16 %0, %1, %2, %0" : "+v"(oA[nt_]) : "v"(paA), "v"(vb));
        asm("v_mfma_f32_16x16x16_bf16 %0, %1, %2, %0" : "+v"(oB[nt_]) : "v"(paB), "v"(vb));
      }
      __builtin_amdgcn_s_setprio(0);
    }
    denA += __shfl_xor(denA, 16);
    denA += __shfl_xor(denA, 32);
    denB += __shfl_xor(denB, 16);
    denB += __shfl_xor(denB, 32);
    float invA = 1.0f / denA, invB = 1.0f / denB;
    float invrA[4], invrB[4];
#pragma unroll
    for (int r = 0; r < 4; r++) {
      invrA[r] = __shfl(invA, g * 4 + r);
      invrB[r] = __shfl(invB, g * 4 + r);
    }

#pragma unroll
    for (int nt_ = 0; nt_ < 4; nt_++)
#pragma unroll
      for (int r = 0; r < 4; r++) {
        int sA_ = q0 + g * 4 + r;
        if (sA_ < 196)
          AO[((long)(b * 196 + sA_)) * 768 + nh * 64 + nt_ * 16 + q15] = f2bf(oA[nt_][r] * invrA[r]);
        int sB_ = q0 + 16 + g * 4 + r;
        if (sB_ < 196)
          AO[((long)(b * 196 + sB_)) * 768 + nh * 64 + nt_ * 16 + q15] = f2bf(oB[nt_][r] * invrB[r]);
      }
  }
}

// ---------------- launch ----------------
#define GEMM_LDS 131072

extern "C" void kernel_launch(void* const* d_in, const int* in_sizes, int n_in,
                              void* d_out, int out_size, void* d_ws, size_t ws_size,
                              hipStream_t stream) {
  const float* hs = (const float*)d_in[0];
  const float* qkvw = (const float*)d_in[1];
  const float* qkvb = (const float*)d_in[2];
  const float* projw = (const float*)d_in[3];
  const float* projb = (const float*)d_in[4];
  const float* rph = (const float*)d_in[5];
  const float* rpw = (const float*)d_in[6];

  char* ws = (char*)d_ws;
  u16* Xb = (u16*)ws;                        // 120,422,400 B — attention output only now
  u16* Wq = (u16*)(ws + 120422400);          // 3,538,944 B (reused as IndK table after qkv)
  u16* Wp = (u16*)(ws + 123961344);          // 1,179,648 B
  u16* Qb = (u16*)(ws + 125140992);          // 120,422,400 B
  u16* Kb = (u16*)(ws + 245563392);          // 120,422,400 B
  u16* Vb = (u16*)(ws + 365985792);          // 120,422,400 B
  u16* AO = Xb;
  u16* IndKg = Wq;                           // alias: valid only after qkv_gemm

  cvt_f32_bf16<<<864, 256, 0, stream>>>(qkvw, Wq, 221184);
  cvt_f32_bf16<<<288, 256, 0, stream>>>(projw, Wp, 73728);

  hipFuncSetAttribute((const void*)qkv_gemm, hipFuncAttributeMaxDynamicSharedMemorySize, GEMM_LDS);
  qkv_gemm<<<2763, 512, GEMM_LDS, stream>>>(hs, Wq, qkvb, Qb, Kb, Vb);

  indk_init<<<33, 256, 0, stream>>>(IndKg);

  hipFuncSetAttribute((const void*)attn_kernel, hipFuncAttributeMaxDynamicSharedMemorySize, SMEM_SZ);
  attn_kernel<<<4800, 512, SMEM_SZ, stream>>>(Qb, Kb, Vb, rph, rpw, IndKg, AO);

  hipFuncSetAttribute((const void*)proj_gemm, hipFuncAttributeMaxDynamicSharedMemorySize, GEMM_LDS);
  proj_gemm<<<921, 512, GEMM_LDS, stream>>>(AO, Wp, projb, (float*)d_out);
}

// Round 11
// 742.817 us; speedup vs baseline: 1.1104x; 1.1104x over previous
//
#include <hip/hip_runtime.h>
#include <hip/hip_bf16.h>

typedef __bf16 bfv8 __attribute__((ext_vector_type(8)));
typedef __bf16 bfv4 __attribute__((ext_vector_type(4)));
typedef float f32x4 __attribute__((ext_vector_type(4)));
typedef unsigned int u32x2 __attribute__((ext_vector_type(2)));
typedef unsigned short u16;
typedef unsigned int u32;

#define MT 78400   // total tokens = 400*196

#define SBAR() __builtin_amdgcn_s_barrier()
#define VMCNT(n) asm volatile("s_waitcnt vmcnt(" #n ")" ::: "memory")

__device__ __forceinline__ u16 f2bf(float f) {
  u32 x = __float_as_uint(f);
  return (u16)((x + 0x7FFFu + ((x >> 16) & 1u)) >> 16);
}

__device__ __forceinline__ void gld16(const void* g, void* l) {
  __builtin_amdgcn_global_load_lds((const __attribute__((address_space(1))) void*)g,
                                   (__attribute__((address_space(3))) void*)l, 16, 0, 0);
}

// ---------------- fp32 -> bf16 convert (hidden states) ----------------
__global__ __launch_bounds__(256) void cvt_f32_bf16(const float* __restrict__ src,
                                                    u16* __restrict__ dst, int n8) {
  int stride = gridDim.x * 256;
  for (int i = blockIdx.x * 256 + threadIdx.x; i < n8; i += stride) {
    const float4* s = (const float4*)(src + (long)i * 8);
    float4 a = s[0], b = s[1];
    u32 p0 = f2bf(a.x) | ((u32)f2bf(a.y) << 16);
    u32 p1 = f2bf(a.z) | ((u32)f2bf(a.w) << 16);
    u32 p2 = f2bf(b.x) | ((u32)f2bf(b.y) << 16);
    u32 p3 = f2bf(b.z) | ((u32)f2bf(b.w) << 16);
    uint4 o = {p0, p1, p2, p3};
    *(uint4*)(dst + (long)i * 8) = o;
  }
}

// ---------------- both weight converts in ONE launch (saves a launch) ----------------
// qkvw: 221184 chunks of 8 -> Wq ; projw: 73728 chunks -> Wp. grid = 1152 x 256.
__global__ __launch_bounds__(256) void cvt_weights(const float* __restrict__ qkvw, u16* __restrict__ Wq,
                                                   const float* __restrict__ projw, u16* __restrict__ Wp) {
  int i = blockIdx.x * 256 + threadIdx.x;    // 0 .. 294911
  const float* src; u16* dst; int j;
  if (i < 221184) { src = qkvw; dst = Wq; j = i; }
  else            { src = projw; dst = Wp; j = i - 221184; }
  const float4* s = (const float4*)(src + (long)j * 8);
  float4 a = s[0], b = s[1];
  u32 p0 = f2bf(a.x) | ((u32)f2bf(a.y) << 16);
  u32 p1 = f2bf(a.z) | ((u32)f2bf(a.w) << 16);
  u32 p2 = f2bf(b.x) | ((u32)f2bf(b.y) << 16);
  u32 p3 = f2bf(b.z) | ((u32)f2bf(b.w) << 16);
  uint4 o = {p0, p1, p2, p3};
  *(uint4*)(dst + (long)j * 8) = o;
}

// ---------------- one-hot indicator table for rel-pos bias (global const) ----------------
__global__ __launch_bounds__(256) void indk_init(u16* __restrict__ T) {
  int i = blockIdx.x * 256 + threadIdx.x;
  if (i < 208 * 40) {
    int k = i / 40, j = i - (i / 40) * 40;
    int hk = k / 14, wk = k - hk * 14;
    T[i] = (j == hk || j == 16 + wk) ? 0x3F80 : 0;
  }
}

// ================= 256x256 / BK=64 / 8-wave GEMM core (round-3 verified; 861 TF) =================
__device__ __forceinline__ void gemm256_main(const u16* __restrict__ A, const u16* __restrict__ W,
                                             u16* SH, int m0, int n0, int tid,
                                             f32x4 (&acc)[8][4]) {
  const int lane = tid & 63;
  const int q15 = lane & 15, g = lane >> 4;
  const int wid = tid >> 6;
  const int wm = wid >> 2, wn = wid & 3;   // 2 x 4 waves; per-wave C = 128 x 64
  const int x0 = (g ^ (q15 & 7)) << 3;     // swizzled u16 offset of ksub0 (ksub1 = x0^32)
  const int arow0 = wm * 128 + q15;
  const int brow0 = wn * 64 + q15;

  // ---- hoisted staging sources ----
  const int r0 = tid >> 3;
  const int gc0 = ((tid & 7) ^ (r0 & 7)) << 3;   // u16 offset, pre-swizzled
  int ra00 = m0 + r0;       if (ra00 > MT - 1) ra00 = MT - 1;
  int ra10 = m0 + 64 + r0;  if (ra10 > MT - 1) ra10 = MT - 1;
  int ra01 = m0 + 128 + r0; if (ra01 > MT - 1) ra01 = MT - 1;
  int ra11 = m0 + 192 + r0; if (ra11 > MT - 1) ra11 = MT - 1;
  const u16* aS00 = A + (long)ra00 * 768 + gc0;
  const u16* aS10 = A + (long)ra10 * 768 + gc0;
  const u16* aS01 = A + (long)ra01 * 768 + gc0;
  const u16* aS11 = A + (long)ra11 * 768 + gc0;
  const u16* bS00 = W + (long)(n0 + r0) * 768 + gc0;
  const u16* bS10 = W + (long)(n0 + 64 + r0) * 768 + gc0;
  const u16* bS01 = W + (long)(n0 + 128 + r0) * 768 + gc0;
  const u16* bS11 = W + (long)(n0 + 192 + r0) * 768 + gc0;
  u16* dA = SH + tid * 8;
  u16* dB = dA + 16384;

  auto STGA = [&](int sl, const u16* p0, const u16* p1, int hoff, int kt) {
    u16* d = dA + sl * 32768 + hoff;
    gld16(p0 + kt * 64, d);
    gld16(p1 + kt * 64, d + 4096);
  };
  auto STGB = [&](int sl, const u16* p0, const u16* p1, int hoff, int kt) {
    u16* d = dB + sl * 32768 + hoff;
    gld16(p0 + kt * 64, d);
    gld16(p1 + kt * 64, d + 4096);
  };

  bfv8 b0[4], b1[4];
  bfv8 aX0[2], aX1[2], aY0[2], aY1[2];

  STGB(0, bS00, bS10, 0, 0); STGB(0, bS01, bS11, 8192, 0);
  STGA(0, aS00, aS10, 0, 0); STGA(0, aS01, aS11, 8192, 0);
  STGB(1, bS00, bS10, 0, 1); STGB(1, bS01, bS11, 8192, 1);
  STGA(1, aS00, aS10, 0, 1);
  VMCNT(4);
  SBAR();
  {
    const u16* Sb = SH + 16384;
#pragma unroll
    for (int ni = 0; ni < 4; ++ni) {
      const u16* bp = Sb + (brow0 + ni * 16) * 64;
      b0[ni] = *(const bfv8*)(bp + x0);
      b1[ni] = *(const bfv8*)(bp + (x0 ^ 32));
    }
#pragma unroll
    for (int m2 = 0; m2 < 2; ++m2) {
      const u16* ap = SH + (arow0 + m2 * 16) * 64;
      aX0[m2] = *(const bfv8*)(ap + x0);
      aX1[m2] = *(const bfv8*)(ap + (x0 ^ 32));
    }
  }

  for (int u = 0; u < 12; ++u) {
    const int sl = u & 1;
    const u16* Sa = SH + sl * 32768;
    const u16* San = SH + (sl ^ 1) * 32768;
    const u16* Sbn = San + 16384;
    const int kn1 = (u + 1 < 12) ? u + 1 : 11;
    const int kn2 = (u + 2 < 12) ? u + 2 : 11;

    // q0
    __builtin_amdgcn_s_setprio(1);
#pragma unroll
    for (int m2 = 0; m2 < 2; ++m2)
#pragma unroll
      for (int ni = 0; ni < 4; ++ni)
        acc[m2][ni] = __builtin_amdgcn_mfma_f32_16x16x32_bf16(aX0[m2], b0[ni], acc[m2][ni], 0, 0, 0);
#pragma unroll
    for (int m2 = 0; m2 < 2; ++m2)
#pragma unroll
      for (int ni = 0; ni < 4; ++ni)
        acc[m2][ni] = __builtin_amdgcn_mfma_f32_16x16x32_bf16(aX1[m2], b1[ni], acc[m2][ni], 0, 0, 0);
    __builtin_amdgcn_s_setprio(0);
    SBAR();
#pragma unroll
    for (int m2 = 0; m2 < 2; ++m2) {
      const u16* ap = Sa + (arow0 + (2 + m2) * 16) * 64;
      aY0[m2] = *(const bfv8*)(ap + x0);
      aY1[m2] = *(const bfv8*)(ap + (x0 ^ 32));
    }
    STGA(sl ^ 1, aS01, aS11, 8192, kn1);

    // q1
    __builtin_amdgcn_s_setprio(1);
#pragma unroll
    for (int m2 = 0; m2 < 2; ++m2)
#pragma unroll
      for (int ni = 0; ni < 4; ++ni)
        acc[2 + m2][ni] = __builtin_amdgcn_mfma_f32_16x16x32_bf16(aY0[m2], b0[ni], acc[2 + m2][ni], 0, 0, 0);
#pragma unroll
    for (int m2 = 0; m2 < 2; ++m2)
#pragma unroll
      for (int ni = 0; ni < 4; ++ni)
        acc[2 + m2][ni] = __builtin_amdgcn_mfma_f32_16x16x32_bf16(aY1[m2], b1[ni], acc[2 + m2][ni], 0, 0, 0);
    __builtin_amdgcn_s_setprio(0);
    SBAR();
#pragma unroll
    for (int m2 = 0; m2 < 2; ++m2) {
      const u16* ap = Sa + (arow0 + (4 + m2) * 16) * 64;
      aX0[m2] = *(const bfv8*)(ap + x0);
      aX1[m2] = *(const bfv8*)(ap + (x0 ^ 32));
    }
    STGB(sl, bS00, bS10, 0, kn2);

    // q2
    __builtin_amdgcn_s_setprio(1);
#pragma unroll
    for (int m2 = 0; m2 < 2; ++m2)
#pragma unroll
      for (int ni = 0; ni < 4; ++ni)
        acc[4 + m2][ni] = __builtin_amdgcn_mfma_f32_16x16x32_bf16(aX0[m2], b0[ni], acc[4 + m2][ni], 0, 0, 0);
#pragma unroll
    for (int m2 = 0; m2 < 2; ++m2)
#pragma unroll
      for (int ni = 0; ni < 4; ++ni)
        acc[4 + m2][ni] = __builtin_amdgcn_mfma_f32_16x16x32_bf16(aX1[m2], b1[ni], acc[4 + m2][ni], 0, 0, 0);
    __builtin_amdgcn_s_setprio(0);
    SBAR();
#pragma unroll
    for (int m2 = 0; m2 < 2; ++m2) {
      const u16* ap = Sa + (arow0 + (6 + m2) * 16) * 64;
      aY0[m2] = *(const bfv8*)(ap + x0);
      aY1[m2] = *(const bfv8*)(ap + (x0 ^ 32));
    }
    STGB(sl, bS01, bS11, 8192, kn2);

    // q3
    __builtin_amdgcn_s_setprio(1);
#pragma unroll
    for (int m2 = 0; m2 < 2; ++m2)
#pragma unroll
      for (int ni = 0; ni < 4; ++ni)
        acc[6 + m2][ni] = __builtin_amdgcn_mfma_f32_16x16x32_bf16(aY0[m2], b0[ni], acc[6 + m2][ni], 0, 0, 0);
#pragma unroll
    for (int m2 = 0; m2 < 2; ++m2)
#pragma unroll
      for (int ni = 0; ni < 4; ++ni)
        acc[6 + m2][ni] = __builtin_amdgcn_mfma_f32_16x16x32_bf16(aY1[m2], b1[ni], acc[6 + m2][ni], 0, 0, 0);
    __builtin_amdgcn_s_setprio(0);
    VMCNT(4);
    SBAR();
    if (u < 11) {
#pragma unroll
      for (int ni = 0; ni < 4; ++ni) {
        const u16* bp = Sbn + (brow0 + ni * 16) * 64;
        b0[ni] = *(const bfv8*)(bp + x0);
        b1[ni] = *(const bfv8*)(bp + (x0 ^ 32));
      }
#pragma unroll
      for (int m2 = 0; m2 < 2; ++m2) {
        const u16* ap = San + (arow0 + m2 * 16) * 64;
        aX0[m2] = *(const bfv8*)(ap + x0);
        aX1[m2] = *(const bfv8*)(ap + (x0 ^ 32));
      }
    }
    STGA(sl, aS00, aS10, 0, kn2);
  }
  VMCNT(0);
}

// ---------------- QKV GEMM: 256x256 ----------------
__global__ __launch_bounds__(512, 2) void qkv_gemm(const u16* __restrict__ A, const u16* __restrict__ W,
                                                   const float* __restrict__ bias,
                                                   u16* __restrict__ Qo, u16* __restrict__ Ko,
                                                   u16* __restrict__ Vo) {
  extern __shared__ u16 SH[];
  const int tid = threadIdx.x;
  const int orig = blockIdx.x;
  const int xcd = orig & 7, ii = orig >> 3;
  const int wg = (xcd < 3 ? xcd * 346 : 1038 + (xcd - 3) * 345) + ii;
  const int mt = wg / 9, nt = wg - mt * 9;
  const int m0 = mt * 256, n0 = nt * 256;

  f32x4 acc[8][4];
#pragma unroll
  for (int i = 0; i < 8; ++i)
#pragma unroll
    for (int j = 0; j < 4; ++j) acc[i][j] = (f32x4){0.f, 0.f, 0.f, 0.f};

  gemm256_main(A, W, SH, m0, n0, tid, acc);

  const int lane = tid & 63, q15 = lane & 15, g = lane >> 4;
  const int wid = tid >> 6, wm = wid >> 2, wn = wid & 3;
  __syncthreads();
  const int sel = nt / 3;
  u16* dst = (sel == 0) ? Qo : (sel == 1) ? Ko : Vo;
  const int ntr = nt - sel * 3;
  u16* Cs = SH;                             // [128][264]

#pragma unroll
  for (int h = 0; h < 2; ++h) {
    if (wm == h) {
#pragma unroll
      for (int ni = 0; ni < 4; ++ni) {
        int col = wn * 64 + ni * 16 + q15;
        float bb = bias[n0 + col];
#pragma unroll
        for (int mi = 0; mi < 8; ++mi)
#pragma unroll
          for (int r = 0; r < 4; ++r)
            Cs[(mi * 16 + g * 4 + r) * 264 + col] = f2bf(acc[mi][ni][r] + bb);
      }
    }
    __syncthreads();
#pragma unroll
    for (int j = 0; j < 8; ++j) {
      int idx = tid + 512 * j;
      int row = idx >> 5, cc = idx & 31;
      int m = m0 + h * 128 + row;
      if (m < MT) {
        int b = m / 196, s = m - b * 196;
        int nh = ntr * 4 + (cc >> 3);
        int hd0 = (cc & 7) * 8;
        uint4 v = *(const uint4*)(Cs + row * 264 + cc * 8);
        *(uint4*)(dst + (long)b * 150528 + (long)s * 64 + nh * 12544 + hd0) = v;
      }
    }
    if (h == 0) __syncthreads();
  }
}

// ---------------- Proj GEMM: 256x256, f32 output ----------------
__global__ __launch_bounds__(512, 2) void proj_gemm(const u16* __restrict__ A, const u16* __restrict__ W,
                                                    const float* __restrict__ bias,
                                                    float* __restrict__ out) {
  extern __shared__ u16 SH[];
  const int tid = threadIdx.x;
  const int orig = blockIdx.x;
  const int xcd = orig & 7, ii = orig >> 3;
  const int wg = (xcd < 1 ? xcd * 116 : 116 + (xcd - 1) * 115) + ii;
  const int mt = wg / 3, nt = wg - mt * 3;
  const int m0 = mt * 256, n0 = nt * 256;

  f32x4 acc[8][4];
#pragma unroll
  for (int i = 0; i < 8; ++i)
#pragma unroll
    for (int j = 0; j < 4; ++j) acc[i][j] = (f32x4){0.f, 0.f, 0.f, 0.f};

  gemm256_main(A, W, SH, m0, n0, tid, acc);

  const int lane = tid & 63, q15 = lane & 15, g = lane >> 4;
  const int wid = tid >> 6, wm = wid >> 2, wn = wid & 3;

#pragma unroll
  for (int ni = 0; ni < 4; ++ni) {
    int n = n0 + wn * 64 + ni * 16 + q15;
    float bb = bias[n];
#pragma unroll
    for (int mi = 0; mi < 8; ++mi)
#pragma unroll
      for (int r = 0; r < 4; ++r) {
        int m = m0 + wm * 128 + mi * 16 + g * 4 + r;
        if (m < MT) out[(long)m * 768 + n] = acc[mi][ni][r] + bb;
      }
  }
}

// ---------------- fused rel-pos attention (round-8 double-tile) ----------------
#define KLDS_OFF 0          // 208*64*2   = 26624
#define VT_OFF   26624      // 64*256*2   = 32768
#define TH_OFF   59392      // 27*72*2    = 3888
#define TW_OFF   63280      // 3888
#define AW_OFF   67168      // 8*16*40*2  = 10240
#define SMEM_SZ  77408

__global__ __launch_bounds__(512, 2) void attn_kernel(const u16* __restrict__ Q, const u16* __restrict__ K,
                                                      const u16* __restrict__ V,
                                                      const float* __restrict__ rph, const float* __restrict__ rpw,
                                                      const u16* __restrict__ IndKg,
                                                      u16* __restrict__ AO) {
  extern __shared__ char smem[];
  u16* Klds = (u16*)(smem + KLDS_OFF);
  u16* VT = (u16*)(smem + VT_OFF);
  u16* TH = (u16*)(smem + TH_OFF);
  u16* TW = (u16*)(smem + TW_OFF);
  const int tid = threadIdx.x, lane = tid & 63, wid = tid >> 6;
  const int q15 = lane & 15, g = lane >> 4;
  const int bnh = blockIdx.x;
  const int b = bnh / 12, nh = bnh - b * 12;
  const u16* Qg = Q + bnh * 12544;
  const u16* Kg = K + bnh * 12544;
  const u16* Vg = V + bnh * 12544;
  u16* AWw = (u16*)(smem + AW_OFF) + wid * 16 * 40;

  for (int c = tid; c < 1568; c += 512) {
    int krow = c >> 3, part = c & 7;
    gld16(Kg + krow * 64 + ((part ^ (krow & 7)) << 3), Klds + c * 8);
  }
  for (int idx = tid; idx < 1792; idx += 512) {
    int k = idx >> 3, nb = idx & 7;
    u32 w0 = 0, w1 = 0, w2 = 0, w3 = 0;
    if (k < 196) {
      uint4 t = *(const uint4*)(Vg + k * 64 + nb * 8);
      w0 = t.x; w1 = t.y; w2 = t.z; w3 = t.w;
    }
    u32 wv[4] = {w0, w1, w2, w3};
#pragma unroll
    for (int j = 0; j < 8; j++) {
      int n = nb * 8 + j;
      u16 val = (u16)(wv[j >> 1] >> ((j & 1) * 16));
      int blk = (k >> 3) ^ (n & 7) ^ (n >> 3);
      VT[n * 256 + blk * 8 + (k & 7)] = val;
    }
  }
  for (int i = tid; i < 27 * 64; i += 512) {
    int r = i >> 6, cc = i & 63;
    TH[r * 72 + cc] = f2bf(rph[i]);
    TW[r * 72 + cc] = f2bf(rpw[i]);
  }
  __syncthreads();

  const int ksw = q15 & 7;
  const int ko0 = (g ^ ksw) << 3;
  const int ko1 = ((g + 4) ^ ksw) << 3;
  const f32x4 zero = {0.f, 0.f, 0.f, 0.f};

  auto mk_qaug = [&](int tq0, bfv8 qf0, bfv8 qf1) -> bfv8 {
    int hq0 = tq0 / 14, hq1 = (tq0 + 15) / 14;
    int rha = hq0 + 13 - q15; rha = rha < 0 ? 0 : (rha > 26 ? 26 : rha);
    int rhb = hq1 + 13 - q15; rhb = rhb < 0 ? 0 : (rhb > 26 ? 26 : rhb);
    int rwa = q15;
    int rwb = 16 + q15; if (rwb > 26) rwb = 26;
    f32x4 c0h = zero, c1h = zero, c0w = zero, c1w = zero;
    {
      bfv8 t0 = *(const bfv8*)(TH + rha * 72 + g * 8);
      bfv8 t1 = *(const bfv8*)(TH + rha * 72 + 32 + g * 8);
      c0h = __builtin_amdgcn_mfma_f32_16x16x32_bf16(qf0, t0, c0h, 0, 0, 0);
      c0h = __builtin_amdgcn_mfma_f32_16x16x32_bf16(qf1, t1, c0h, 0, 0, 0);
      bfv8 t2 = *(const bfv8*)(TH + rhb * 72 + g * 8);
      bfv8 t3 = *(const bfv8*)(TH + rhb * 72 + 32 + g * 8);
      c1h = __builtin_amdgcn_mfma_f32_16x16x32_bf16(qf0, t2, c1h, 0, 0, 0);
      c1h = __builtin_amdgcn_mfma_f32_16x16x32_bf16(qf1, t3, c1h, 0, 0, 0);
      bfv8 u0 = *(const bfv8*)(TW + rwa * 72 + g * 8);
      bfv8 u1 = *(const bfv8*)(TW + rwa * 72 + 32 + g * 8);
      c0w = __builtin_amdgcn_mfma_f32_16x16x32_bf16(qf0, u0, c0w, 0, 0, 0);
      c0w = __builtin_amdgcn_mfma_f32_16x16x32_bf16(qf1, u1, c0w, 0, 0, 0);
      bfv8 u2 = *(const bfv8*)(TW + rwb * 72 + g * 8);
      bfv8 u3 = *(const bfv8*)(TW + rwb * 72 + 32 + g * 8);
      c1w = __builtin_amdgcn_mfma_f32_16x16x32_bf16(qf0, u2, c1w, 0, 0, 0);
      c1w = __builtin_amdgcn_mfma_f32_16x16x32_bf16(qf1, u3, c1w, 0, 0, 0);
    }
#pragma unroll
    for (int r = 0; r < 4; r++) {
      int row = g * 4 + r;
      int qq = tq0 + row;
      int hqr = qq / 14;
      int wq_r = qq - hqr * 14;
      if (q15 < 10) AWw[row * 40 + 30 + q15] = 0;
      float rh = ((hqr == hq1) ? c1h[r] : c0h[r]) * 8.0f;
      AWw[row * 40 + q15] = (q15 <= 13) ? f2bf(rh) : (u16)0;
      int w0p = wq_r + 13 - q15;
      if (w0p >= 0 && w0p <= 13) AWw[row * 40 + 16 + w0p] = f2bf(c0w[r] * 8.0f);
      int w1p = wq_r - 3 - q15;
      if (w1p >= 0 && w1p <= 13) AWw[row * 40 + 16 + w1p] = f2bf(c1w[r] * 8.0f);
    }
    return *(const bfv8*)(AWw + q15 * 40 + g * 8);
  };

  if (wid < 7) {
    const int q0 = wid * 32;
    int qrA = q0 + q15;      if (qrA > 195) qrA = 195;
    int qrB = q0 + 16 + q15; if (qrB > 195) qrB = 195;
    bfv8 qf0A = *(const bfv8*)(Qg + qrA * 64 + g * 8);
    bfv8 qf1A = *(const bfv8*)(Qg + qrA * 64 + 32 + g * 8);
    bfv8 qf0B = *(const bfv8*)(Qg + qrB * 64 + g * 8);
    bfv8 qf1B = *(const bfv8*)(Qg + qrB * 64 + 32 + g * 8);

    bfv8 qaugA = mk_qaug(q0, qf0A, qf1A);
    bfv8 qaugB = mk_qaug(q0 + 16, qf0B, qf1B);

    f32x4 oA[4] = {zero, zero, zero, zero};
    f32x4 oB[4] = {zero, zero, zero, zero};
    float denA = 0.f, denB = 0.f;
#pragma unroll
    for (int t = 0; t < 13; t++) {
      const u16* kr = Klds + (t * 16 + q15) * 64;
      bfv8 kb0 = *(const bfv8*)(kr + ko0);
      bfv8 kb1 = *(const bfv8*)(kr + ko1);
      bfv8 ib = *(const bfv8*)(IndKg + (t * 16 + q15) * 40 + g * 8);
      __builtin_amdgcn_s_setprio(1);
      f32x4 aA = __builtin_amdgcn_mfma_f32_16x16x32_bf16(ib, qaugA, zero, 0, 0, 0);
      f32x4 aB = __builtin_amdgcn_mfma_f32_16x16x32_bf16(ib, qaugB, zero, 0, 0, 0);
      aA = __builtin_amdgcn_mfma_f32_16x16x32_bf16(kb0, qf0A, aA, 0, 0, 0);
      aB = __builtin_amdgcn_mfma_f32_16x16x32_bf16(kb0, qf0B, aB, 0, 0, 0);
      f32x4 sA = __builtin_amdgcn_mfma_f32_16x16x32_bf16(kb1, qf1A, aA, 0, 0, 0);
      f32x4 sB = __builtin_amdgcn_mfma_f32_16x16x32_bf16(kb1, qf1B, aB, 0, 0, 0);
      __builtin_amdgcn_s_setprio(0);
      const bool msk = (t == 12 && g > 0);
      float pA0 = msk ? 0.f : exp2f(sA[0] * 0.18033688f - 5.7707802f);
      float pA1 = msk ? 0.f : exp2f(sA[1] * 0.18033688f - 5.7707802f);
      float pA2 = msk ? 0.f : exp2f(sA[2] * 0.18033688f - 5.7707802f);
      float pA3 = msk ? 0.f : exp2f(sA[3] * 0.18033688f - 5.7707802f);
      float pB0 = msk ? 0.f : exp2f(sB[0] * 0.18033688f - 5.7707802f);
      float pB1 = msk ? 0.f : exp2f(sB[1] * 0.18033688f - 5.7707802f);
      float pB2 = msk ? 0.f : exp2f(sB[2] * 0.18033688f - 5.7707802f);
      float pB3 = msk ? 0.f : exp2f(sB[3] * 0.18033688f - 5.7707802f);
      denA += (pA0 + pA1) + (pA2 + pA3);
      denB += (pB0 + pB1) + (pB2 + pB3);
      u32 loA, hiA, loB, hiB;
      asm("v_cvt_pk_bf16_f32 %0, %1, %2" : "=v"(loA) : "v"(pA0), "v"(pA1));
      asm("v_cvt_pk_bf16_f32 %0, %1, %2" : "=v"(hiA) : "v"(pA2), "v"(pA3));
      asm("v_cvt_pk_bf16_f32 %0, %1, %2" : "=v"(loB) : "v"(pB0), "v"(pB1));
      asm("v_cvt_pk_bf16_f32 %0, %1, %2" : "=v"(hiB) : "v"(pB2), "v"(pB3));
      u32x2 wA; wA.x = loA; wA.y = hiA;
      u32x2 wB; wB.x = loB; wB.y = hiB;
      bfv4 paA = __builtin_bit_cast(bfv4, wA);
      bfv4 paB = __builtin_bit_cast(bfv4, wB);
      const int kblk = 2 * t + (g >> 1);
      const int koff = (g & 1) * 4;
      __builtin_amdgcn_s_setprio(1);
#pragma unroll
      for (int nt_ = 0; nt_ < 4; nt_++) {
        int n = nt_ * 16 + q15;
        int blk = (kblk ^ (n & 7) ^ (n >> 3));
        bfv4 vb = *(const bfv4*)(VT + n * 256 + blk * 8 + koff);
        asm("v_mfma_f32_16x16x16_bf16 %0, %1, %2, %0" : "+v"(oA[nt_]) : "v"(paA), "v"(vb));
        asm("v_mfma_f32_16x16x16_bf16 %0, %1, %2, %0" : "+v"(oB[nt_]) : "v"(paB), "v"(vb));
      }
      __builtin_amdgcn_s_setprio(0);
    }
    denA += __shfl_xor(denA, 16);
    denA += __shfl_xor(denA, 32);
    denB += __shfl_xor(denB, 16);
    denB += __shfl_xor(denB, 32);
    float invA = 1.0f / denA, invB = 1.0f / denB;
    float invrA[4], invrB[4];
#pragma unroll
    for (int r = 0; r < 4; r++) {
      invrA[r] = __shfl(invA, g * 4 + r);
      invrB[r] = __shfl(invB, g * 4 + r);
    }

#pragma unroll
    for (int nt_ = 0; nt_ < 4; nt_++)
#pragma unroll
      for (int r = 0; r < 4; r++) {
        int sA_ = q0 + g * 4 + r;
        if (sA_ < 196)
          AO[((long)(b * 196 + sA_)) * 768 + nh * 64 + nt_ * 16 + q15] = f2bf(oA[nt_][r] * invrA[r]);
        int sB_ = q0 + 16 + g * 4 + r;
        if (sB_ < 196)
          AO[((long)(b * 196 + sB_)) * 768 + nh * 64 + nt_ * 16 + q15] = f2bf(oB[nt_][r] * invrB[r]);
      }
  }
}

// ---------------- launch ----------------
#define GEMM_LDS 131072

extern "C" void kernel_launch(void* const* d_in, const int* in_sizes, int n_in,
                              void* d_out, int out_size, void* d_ws, size_t ws_size,
                              hipStream_t stream) {
  const float* hs = (const float*)d_in[0];
  const float* qkvw = (const float*)d_in[1];
  const float* qkvb = (const float*)d_in[2];
  const float* projw = (const float*)d_in[3];
  const float* projb = (const float*)d_in[4];
  const float* rph = (const float*)d_in[5];
  const float* rpw = (const float*)d_in[6];

  char* ws = (char*)d_ws;
  u16* Xb = (u16*)ws;                        // 120,422,400 B (cvt'd hs; reused as attention output)
  u16* Wq = (u16*)(ws + 120422400);          // 3,538,944 B (reused as IndK table after qkv)
  u16* Wp = (u16*)(ws + 123961344);          // 1,179,648 B
  u16* Qb = (u16*)(ws + 125140992);          // 120,422,400 B
  u16* Kb = (u16*)(ws + 245563392);          // 120,422,400 B
  u16* Vb = (u16*)(ws + 365985792);          // 120,422,400 B
  u16* AO = Xb;
  u16* IndKg = Wq;                           // alias: valid only after qkv_gemm

  cvt_f32_bf16<<<2048, 256, 0, stream>>>(hs, Xb, 7526400);
  cvt_weights<<<1152, 256, 0, stream>>>(qkvw, Wq, projw, Wp);

  hipFuncSetAttribute((const void*)qkv_gemm, hipFuncAttributeMaxDynamicSharedMemorySize, GEMM_LDS);
  qkv_gemm<<<2763, 512, GEMM_LDS, stream>>>(Xb, Wq, qkvb, Qb, Kb, Vb);

  indk_init<<<33, 256, 0, stream>>>(IndKg);

  hipFuncSetAttribute((const void*)attn_kernel, hipFuncAttributeMaxDynamicSharedMemorySize, SMEM_SZ);
  attn_kernel<<<4800, 512, SMEM_SZ, stream>>>(Qb, Kb, Vb, rph, rpw, IndKg, AO);

  hipFuncSetAttribute((const void*)proj_gemm, hipFuncAttributeMaxDynamicSharedMemorySize, GEMM_LDS);
  proj_gemm<<<921, 512, GEMM_LDS, stream>>>(AO, Wp, projb, (float*)d_out);
}